// Round 5
// baseline (91.467 us; speedup 1.0000x reference)
//
#include <hip/hip_runtime.h>
#include <cstddef>
#include <cstdint>

namespace {
constexpr int Z    = 4;
constexpr int N    = 256;
constexpr int CIN  = 32;
constexpr int COUT = 32;
constexpr int HID  = 64;
constexpr int OC   = COUT * CIN;  // 1024

typedef _Float16 f16x8 __attribute__((ext_vector_type(8)));
typedef float    f32x4 __attribute__((ext_vector_type(4)));

union H2 { _Float16 h[2]; uint32_t u; };
}

// ---------------------------------------------------------------------------
// Kernel A: M[z][b][o] (o = kc*256 + i*8 + j, h = (kc>>2)*32 + (kc&3)*8 + j)
// split into f16 hi/lo planes. Thread = (i, j-pair): computes j=2jp,2jp+1 and
// stores ONE PACKED DWORD per plane -> wave stores are dense 256 B runs
// (was: scalar 2-byte stores at 16 B stride = half-empty 256 B windows).
// Grid 64 bg x 16 (kc, i-half) = 1024 blocks x 64 thr; 16 (z,b) per block.
// ---------------------------------------------------------------------------
__global__ __launch_bounds__(64) void precompute_M(
    const float* __restrict__ features,
    const float* __restrict__ W2,
    const float* __restrict__ b2,
    _Float16* __restrict__ Mh,
    _Float16* __restrict__ Ml,
    float* __restrict__ bfws)
{
    __shared__ __align__(16) float f_lds[16 * CIN];   // 16 (z,b) x 32 j
    const int blk = blockIdx.x;          // bg*16 + p5
    const int p5  = blk & 15;
    const int bg  = blk >> 4;            // 0..63 (b-quad)
    const int b0  = bg * 4;
    const int t   = threadIdx.x;         // 0..63

    // stage features for all 16 (z, b0..b0+3) pairs
#pragma unroll
    for (int r = 0; r < 8; ++r) {
        const int idx = r * 64 + t;      // 0..511: zb = idx>>5, j = idx&31
        const int zb = idx >> 5;
        f_lds[idx] = features[((zb >> 2) * N + b0 + (zb & 3)) * CIN + (idx & 31)];
    }
    __syncthreads();

    const int kc    = p5 >> 1;           // 0..7
    const int ib    = p5 & 1;
    const int jp    = t >> 4;            // 0..3 (j-pair)
    const int i_loc = t & 15;            // 16 consecutive lanes: i-contiguous
    const int i     = ib * 16 + i_loc;
    const int h0    = (kc >> 2) * 32 + (kc & 3) * 8 + 2 * jp;
    const int o2    = kc * 256 + i * 8 + 2 * jp;   // even halfword slot

    const float4* w2r0 = reinterpret_cast<const float4*>(W2 + (h0 + 0) * OC + i * CIN);
    const float4* w2r1 = reinterpret_cast<const float4*>(W2 + (h0 + 1) * OC + i * CIN);
    float4 w0[8], w1[8];
#pragma unroll
    for (int q = 0; q < 8; ++q) { w0[q] = w2r0[q]; w1[q] = w2r1[q]; }

#pragma unroll
    for (int zb = 0; zb < 16; ++zb) {
        const float4* f4 = reinterpret_cast<const float4*>(&f_lds[zb * CIN]);
        float v0 = 0.f, v1 = 0.f;
#pragma unroll
        for (int q = 0; q < 8; ++q) {
            const float4 f = f4[q];
            v0 += w0[q].x * f.x + w0[q].y * f.y + w0[q].z * f.z + w0[q].w * f.w;
            v1 += w1[q].x * f.x + w1[q].y * f.y + w1[q].z * f.z + w1[q].w * f.w;
        }
        const _Float16 hi0 = (_Float16)v0;
        const _Float16 hi1 = (_Float16)v1;
        H2 ph, pl;
        ph.h[0] = hi0;                      ph.h[1] = hi1;
        pl.h[0] = (_Float16)(v0 - (float)hi0);
        pl.h[1] = (_Float16)(v1 - (float)hi1);
        const size_t base = (size_t)((zb >> 2) * N + b0 + (zb & 3)) * 2048 + o2;
        *reinterpret_cast<uint32_t*>(Mh + base) = ph.u;
        *reinterpret_cast<uint32_t*>(Ml + base) = pl.u;
    }

    // bf[z][b][i] = b2[i*32+..] . f   (p5 = 0,1 blocks, 4 zb per thread)
    if (p5 < 2) {
        const int ii = t & 31, half = t >> 5;
        const float4* b2r = reinterpret_cast<const float4*>(b2 + ii * CIN);
        float4 bb[8];
#pragma unroll
        for (int q = 0; q < 8; ++q) bb[q] = b2r[q];
#pragma unroll
        for (int s = 0; s < 4; ++s) {
            const int zb = p5 * 8 + half * 4 + s;
            const float4* f4 = reinterpret_cast<const float4*>(&f_lds[zb * CIN]);
            float v = 0.f;
#pragma unroll
            for (int q = 0; q < 8; ++q) {
                const float4 f = f4[q];
                v += bb[q].x * f.x + bb[q].y * f.y + bb[q].z * f.z + bb[q].w * f.w;
            }
            bfws[((zb >> 2) * N + b0 + (zb & 3)) * COUT + ii] = v;
        }
    }
}

// ---------------------------------------------------------------------------
// Kernel B: MFMA contraction (unchanged core). Block = 1 wave = 16 a x 4 b.
// Epilogue: stage the 16a x 128col tile in LDS (stride 132 -> only free
// 2-way conflicts on the write side), then 8 x dwordx4 nt stores per lane,
// each instr = two fully-contiguous 512 B a-slabs (was 32 scalar dword
// stores in 64 B chunks at 32 KB stride). nt store uses native ext-vector
// f32x4 (HIP float4 class type is rejected by the builtin).
// ---------------------------------------------------------------------------
__global__ __launch_bounds__(64) void pair_contract_mfma(
    const float* __restrict__ geometry,
    const float* __restrict__ W1,
    const float* __restrict__ b1,
    const _Float16* __restrict__ Mh,
    const _Float16* __restrict__ Ml,
    const float* __restrict__ bfws,
    float* __restrict__ out)
{
    __shared__ __align__(16) float st[16 * 132];   // 8448 B out-staging

    const int blk  = blockIdx.x;         // abk*256 + z*64 + bbk
    const int abk  = blk >> 8;           // 0..15
    const int z    = (blk >> 6) & 3;
    const int bbk  = blk & 63;
    const int a0   = abk * 16;
    const int b0   = bbk * 4;
    const int l    = threadIdx.x;
    const int lo4  = l & 15;
    const int quad = l >> 4;             // 0..3

    // geometry of this lane's A-row
    const float gax = geometry[(z * N + a0 + lo4) * 3 + 0];
    const float gay = geometry[(z * N + a0 + lo4) * 3 + 1];
    const float gaz = geometry[(z * N + a0 + lo4) * 3 + 2];

    // W1 / b1 columns for this lane's h-slots: h = kb*32 + quad*8 + (hf*4+jj)
    float4 w1f[3][2][2], b1f[2][2];
#pragma unroll
    for (int x = 0; x < 3; ++x)
#pragma unroll
        for (int kb = 0; kb < 2; ++kb)
#pragma unroll
            for (int hf = 0; hf < 2; ++hf)
                w1f[x][kb][hf] = *reinterpret_cast<const float4*>(
                    W1 + x * HID + kb * 32 + quad * 8 + hf * 4);
#pragma unroll
    for (int kb = 0; kb < 2; ++kb)
#pragma unroll
        for (int hf = 0; hf < 2; ++hf)
            b1f[kb][hf] = *reinterpret_cast<const float4*>(
                b1 + kb * 32 + quad * 8 + hf * 4);

    f32x4 acc[4][2];
#pragma unroll
    for (int bq = 0; bq < 4; ++bq)
#pragma unroll
        for (int nt = 0; nt < 2; ++nt) acc[bq][nt] = (f32x4)0.f;

#pragma unroll
    for (int bq = 0; bq < 4; ++bq) {
        const int b = b0 + bq;
        // B-fragment loads (dense 16 B/lane)
        const size_t mbase = (size_t)(z * N + b) * 2048;
        f16x8 Bh[2][2], Bl[2][2];
#pragma unroll
        for (int kb = 0; kb < 2; ++kb)
#pragma unroll
            for (int nt = 0; nt < 2; ++nt) {
                const size_t p = mbase +
                    (size_t)(((kb * 4 + quad) * 32) + nt * 16 + lo4) * 8;
                Bh[kb][nt] = *reinterpret_cast<const f16x8*>(Mh + p);
                Bl[kb][nt] = *reinterpret_cast<const f16x8*>(Ml + p);
            }

        // A-fragment: H = relu((g_b - g_a).W1 + b1), split hi/lo
        const float dx = geometry[(z * N + b) * 3 + 0] - gax;
        const float dy = geometry[(z * N + b) * 3 + 1] - gay;
        const float dz = geometry[(z * N + b) * 3 + 2] - gaz;
        f16x8 Ah[2], Al[2];
#pragma unroll
        for (int kb = 0; kb < 2; ++kb)
#pragma unroll
            for (int hf = 0; hf < 2; ++hf)
#pragma unroll
                for (int jj = 0; jj < 4; ++jj) {
                    float hv = b1f[kb][hf][jj];
                    hv = fmaf(dx, w1f[0][kb][hf][jj], hv);
                    hv = fmaf(dy, w1f[1][kb][hf][jj], hv);
                    hv = fmaf(dz, w1f[2][kb][hf][jj], hv);
                    hv = fmaxf(hv, 0.f);
                    const _Float16 hi = (_Float16)hv;
                    Ah[kb][hf * 4 + jj] = hi;
                    Al[kb][hf * 4 + jj] = (_Float16)(hv - (float)hi);
                }

        // 12 MFMAs: 2 n-tiles x 2 k-blocks x 3-term split
#pragma unroll
        for (int nt = 0; nt < 2; ++nt)
#pragma unroll
            for (int kb = 0; kb < 2; ++kb) {
                acc[bq][nt] = __builtin_amdgcn_mfma_f32_16x16x32_f16(
                    Ah[kb], Bh[kb][nt], acc[bq][nt], 0, 0, 0);
                acc[bq][nt] = __builtin_amdgcn_mfma_f32_16x16x32_f16(
                    Ah[kb], Bl[kb][nt], acc[bq][nt], 0, 0, 0);
                acc[bq][nt] = __builtin_amdgcn_mfma_f32_16x16x32_f16(
                    Al[kb], Bh[kb][nt], acc[bq][nt], 0, 0, 0);
            }
    }

    // Epilogue: acc + bf -> LDS tile [a_loc][col], col = bq*32 + nt*16 + lo4.
    // D layout (m89): col i = lo4 (+nt*16), row a = a0 + quad*4 + r.
#pragma unroll
    for (int bq = 0; bq < 4; ++bq) {
#pragma unroll
        for (int nt = 0; nt < 2; ++nt) {
            const float bfv = bfws[(z * N + b0 + bq) * COUT + nt * 16 + lo4];
#pragma unroll
            for (int r = 0; r < 4; ++r)
                st[(quad * 4 + r) * 132 + bq * 32 + nt * 16 + lo4] =
                    acc[bq][nt][r] + bfv;
        }
    }
    __syncthreads();

    // 8 dwordx4 nt stores/lane; instr e covers a-rows 2e, 2e+1: two dense
    // 512 B slabs (col -> (b = b0 + col/32, i = col%32) is flat-contiguous).
#pragma unroll
    for (int e = 0; e < 8; ++e) {
        const int a_loc = e * 2 + (l >> 5);
        const int c4    = l & 31;
        const f32x4 v   = *reinterpret_cast<const f32x4*>(&st[a_loc * 132 + c4 * 4]);
        f32x4* dst = reinterpret_cast<f32x4*>(
            &out[(((size_t)z * N + a0 + a_loc) * N + b0) * COUT + c4 * 4]);
        __builtin_nontemporal_store(v, dst);
    }
}

extern "C" void kernel_launch(void* const* d_in, const int* in_sizes, int n_in,
                              void* d_out, int out_size, void* d_ws, size_t ws_size,
                              hipStream_t stream) {
    const float* features = (const float*)d_in[0];
    const float* geometry = (const float*)d_in[1];
    const float* W1 = (const float*)d_in[2];
    const float* b1 = (const float*)d_in[3];
    const float* W2 = (const float*)d_in[4];
    const float* b2 = (const float*)d_in[5];
    float* out = (float*)d_out;

    // workspace carve: Mh (4 MB) | Ml (4 MB) | bf (128 KB)
    _Float16* Mh  = (_Float16*)d_ws;
    _Float16* Ml  = Mh + (size_t)Z * N * 2048;
    float*    bfw = (float*)(Ml + (size_t)Z * N * 2048);

    precompute_M<<<64 * 16, 64, 0, stream>>>(features, W2, b2, Mh, Ml, bfw);
    pair_contract_mfma<<<16 * Z * 64, 64, 0, stream>>>(
        geometry, W1, b1, Mh, Ml, bfw, out);
}

// Round 6
// 91.462 us; speedup vs baseline: 1.0001x; 1.0001x over previous
//
#include <hip/hip_runtime.h>
#include <cstddef>
#include <cstdint>

namespace {
constexpr int Z    = 4;
constexpr int N    = 256;
constexpr int CIN  = 32;
constexpr int COUT = 32;
constexpr int HID  = 64;
constexpr int OC   = COUT * CIN;  // 1024

typedef _Float16 f16x8 __attribute__((ext_vector_type(8)));
typedef float    f32x4 __attribute__((ext_vector_type(4)));

union H2 { _Float16 h[2]; uint32_t u; };
}

// ---------------------------------------------------------------------------
// Kernel A: M[z][b][o] (o = kc*256 + i*8 + j, h = (kc>>2)*32 + (kc&3)*8 + j)
// split into f16 hi/lo planes; packed-dword stores (dense 256 B wave runs).
// Grid 64 bg x 16 (kc, i-half) = 1024 blocks x 64 thr; 16 (z,b) per block.
// ---------------------------------------------------------------------------
__global__ __launch_bounds__(64) void precompute_M(
    const float* __restrict__ features,
    const float* __restrict__ W2,
    const float* __restrict__ b2,
    _Float16* __restrict__ Mh,
    _Float16* __restrict__ Ml,
    float* __restrict__ bfws)
{
    __shared__ __align__(16) float f_lds[16 * CIN];   // 16 (z,b) x 32 j
    const int blk = blockIdx.x;          // bg*16 + p5
    const int p5  = blk & 15;
    const int bg  = blk >> 4;            // 0..63 (b-quad)
    const int b0  = bg * 4;
    const int t   = threadIdx.x;         // 0..63

#pragma unroll
    for (int r = 0; r < 8; ++r) {
        const int idx = r * 64 + t;      // 0..511: zb = idx>>5, j = idx&31
        const int zb = idx >> 5;
        f_lds[idx] = features[((zb >> 2) * N + b0 + (zb & 3)) * CIN + (idx & 31)];
    }
    __syncthreads();

    const int kc    = p5 >> 1;           // 0..7
    const int ib    = p5 & 1;
    const int jp    = t >> 4;            // 0..3 (j-pair)
    const int i_loc = t & 15;            // 16 consecutive lanes: i-contiguous
    const int i     = ib * 16 + i_loc;
    const int h0    = (kc >> 2) * 32 + (kc & 3) * 8 + 2 * jp;
    const int o2    = kc * 256 + i * 8 + 2 * jp;   // even halfword slot

    const float4* w2r0 = reinterpret_cast<const float4*>(W2 + (h0 + 0) * OC + i * CIN);
    const float4* w2r1 = reinterpret_cast<const float4*>(W2 + (h0 + 1) * OC + i * CIN);
    float4 w0[8], w1[8];
#pragma unroll
    for (int q = 0; q < 8; ++q) { w0[q] = w2r0[q]; w1[q] = w2r1[q]; }

#pragma unroll
    for (int zb = 0; zb < 16; ++zb) {
        const float4* f4 = reinterpret_cast<const float4*>(&f_lds[zb * CIN]);
        float v0 = 0.f, v1 = 0.f;
#pragma unroll
        for (int q = 0; q < 8; ++q) {
            const float4 f = f4[q];
            v0 += w0[q].x * f.x + w0[q].y * f.y + w0[q].z * f.z + w0[q].w * f.w;
            v1 += w1[q].x * f.x + w1[q].y * f.y + w1[q].z * f.z + w1[q].w * f.w;
        }
        const _Float16 hi0 = (_Float16)v0;
        const _Float16 hi1 = (_Float16)v1;
        H2 ph, pl;
        ph.h[0] = hi0;                      ph.h[1] = hi1;
        pl.h[0] = (_Float16)(v0 - (float)hi0);
        pl.h[1] = (_Float16)(v1 - (float)hi1);
        const size_t base = (size_t)((zb >> 2) * N + b0 + (zb & 3)) * 2048 + o2;
        *reinterpret_cast<uint32_t*>(Mh + base) = ph.u;
        *reinterpret_cast<uint32_t*>(Ml + base) = pl.u;
    }

    // bf[z][b][i] = b2[i*32+..] . f   (p5 = 0,1 blocks, 4 zb per thread)
    if (p5 < 2) {
        const int ii = t & 31, half = t >> 5;
        const float4* b2r = reinterpret_cast<const float4*>(b2 + ii * CIN);
        float4 bb[8];
#pragma unroll
        for (int q = 0; q < 8; ++q) bb[q] = b2r[q];
#pragma unroll
        for (int s = 0; s < 4; ++s) {
            const int zb = p5 * 8 + half * 4 + s;
            const float4* f4 = reinterpret_cast<const float4*>(&f_lds[zb * CIN]);
            float v = 0.f;
#pragma unroll
            for (int q = 0; q < 8; ++q) {
                const float4 f = f4[q];
                v += bb[q].x * f.x + bb[q].y * f.y + bb[q].z * f.z + bb[q].w * f.w;
            }
            bfws[((zb >> 2) * N + b0 + (zb & 3)) * COUT + ii] = v;
        }
    }
}

// ---------------------------------------------------------------------------
// Kernel B: MFMA contraction, zero LDS. Block = 1 wave = 16 a x 4 b.
// OPERANDS SWAPPED vs prev rounds: D = M x H (A-operand = M fragment,
// B-operand = H fragment). A/B fragments have IDENTICAL per-lane placement
// for 16x16x32 (lane&15 -> non-k index, lane>>4 -> k-chunk), so the loads
// and fragment construction are unchanged -- only the intrinsic arg order.
// D layout (m89: col=lane&15, row=(lane>>4)*4+reg) becomes rows=i, cols=a:
// each lane holds 4 CONSECUTIVE i for one a -> epilogue is 8 dwordx4 nt
// stores (was 32 scalar). bf folded into MFMA C-in (bf depends only on
// i = row), deleting epilogue adds. Pure work removal; no LDS, no barrier.
// blk = abk*256 + z*64 + bbk: 16 a-sharers of an M-tile on one XCD.
// ---------------------------------------------------------------------------
__global__ __launch_bounds__(64) void pair_contract_mfma(
    const float* __restrict__ geometry,
    const float* __restrict__ W1,
    const float* __restrict__ b1,
    const _Float16* __restrict__ Mh,
    const _Float16* __restrict__ Ml,
    const float* __restrict__ bfws,
    float* __restrict__ out)
{
    const int blk  = blockIdx.x;         // abk*256 + z*64 + bbk
    const int abk  = blk >> 8;           // 0..15
    const int z    = (blk >> 6) & 3;
    const int bbk  = blk & 63;
    const int a0   = abk * 16;
    const int b0   = bbk * 4;
    const int l    = threadIdx.x;
    const int lo4  = l & 15;
    const int quad = l >> 4;             // 0..3

    // geometry of this lane's a-row (a = a0 + lo4)
    const float gax = geometry[(z * N + a0 + lo4) * 3 + 0];
    const float gay = geometry[(z * N + a0 + lo4) * 3 + 1];
    const float gaz = geometry[(z * N + a0 + lo4) * 3 + 2];

    // W1 / b1 columns for this lane's h-slots: h = kb*32 + quad*8 + (hf*4+jj)
    float4 w1f[3][2][2], b1f[2][2];
#pragma unroll
    for (int x = 0; x < 3; ++x)
#pragma unroll
        for (int kb = 0; kb < 2; ++kb)
#pragma unroll
            for (int hf = 0; hf < 2; ++hf)
                w1f[x][kb][hf] = *reinterpret_cast<const float4*>(
                    W1 + x * HID + kb * 32 + quad * 8 + hf * 4);
#pragma unroll
    for (int kb = 0; kb < 2; ++kb)
#pragma unroll
        for (int hf = 0; hf < 2; ++hf)
            b1f[kb][hf] = *reinterpret_cast<const float4*>(
                b1 + kb * 32 + quad * 8 + hf * 4);

    // acc[bq][it]: D rows = i (it*16 + quad*4 + r), cols = a. Init from bf
    // (row-dependent only) -> bias folded into MFMA C-in.
    f32x4 acc[4][2];
#pragma unroll
    for (int bq = 0; bq < 4; ++bq)
#pragma unroll
        for (int it = 0; it < 2; ++it)
            acc[bq][it] = *reinterpret_cast<const f32x4*>(
                bfws + (z * N + b0 + bq) * COUT + it * 16 + quad * 4);

#pragma unroll
    for (int bq = 0; bq < 4; ++bq) {
        const int b = b0 + bq;
        // M fragments (A-operand): lane holds M[i = it*16+lo4? no --
        // A row index = lane&15 = i_local within the it-tile, k-chunk = quad]
        const size_t mbase = (size_t)(z * N + b) * 2048;
        f16x8 Mhf[2][2], Mlf[2][2];
#pragma unroll
        for (int kb = 0; kb < 2; ++kb)
#pragma unroll
            for (int it = 0; it < 2; ++it) {
                const size_t p = mbase +
                    (size_t)(((kb * 4 + quad) * 32) + it * 16 + lo4) * 8;
                Mhf[kb][it] = *reinterpret_cast<const f16x8*>(Mh + p);
                Mlf[kb][it] = *reinterpret_cast<const f16x8*>(Ml + p);
            }

        // H fragment (B-operand): lane holds H[a = lo4][h-chunk quad]
        const float dx = geometry[(z * N + b) * 3 + 0] - gax;
        const float dy = geometry[(z * N + b) * 3 + 1] - gay;
        const float dz = geometry[(z * N + b) * 3 + 2] - gaz;
        f16x8 Hh[2], Hl[2];
#pragma unroll
        for (int kb = 0; kb < 2; ++kb)
#pragma unroll
            for (int hf = 0; hf < 2; ++hf)
#pragma unroll
                for (int jj = 0; jj < 4; ++jj) {
                    float hv = b1f[kb][hf][jj];
                    hv = fmaf(dx, w1f[0][kb][hf][jj], hv);
                    hv = fmaf(dy, w1f[1][kb][hf][jj], hv);
                    hv = fmaf(dz, w1f[2][kb][hf][jj], hv);
                    hv = fmaxf(hv, 0.f);
                    const _Float16 hi = (_Float16)hv;
                    Hh[kb][hf * 4 + jj] = hi;
                    Hl[kb][hf * 4 + jj] = (_Float16)(hv - (float)hi);
                }

        // 12 MFMAs: D = M x H; terms Mh.Hh + Ml.Hh + Mh.Hl
#pragma unroll
        for (int it = 0; it < 2; ++it)
#pragma unroll
            for (int kb = 0; kb < 2; ++kb) {
                acc[bq][it] = __builtin_amdgcn_mfma_f32_16x16x32_f16(
                    Mhf[kb][it], Hh[kb], acc[bq][it], 0, 0, 0);
                acc[bq][it] = __builtin_amdgcn_mfma_f32_16x16x32_f16(
                    Mlf[kb][it], Hh[kb], acc[bq][it], 0, 0, 0);
                acc[bq][it] = __builtin_amdgcn_mfma_f32_16x16x32_f16(
                    Mhf[kb][it], Hl[kb], acc[bq][it], 0, 0, 0);
            }
    }

    // Epilogue: lane's acc[bq][it] = out[z, a0+lo4, b0+bq, it*16+quad*4 .. +3]
    // -> 8 contiguous 16 B nt stores, 64 B contiguous per quad-group.
#pragma unroll
    for (int bq = 0; bq < 4; ++bq)
#pragma unroll
        for (int it = 0; it < 2; ++it) {
            f32x4* dst = reinterpret_cast<f32x4*>(
                &out[(((size_t)z * N + a0 + lo4) * N + b0 + bq) * COUT +
                     it * 16 + quad * 4]);
            __builtin_nontemporal_store(acc[bq][it], dst);
        }
}

extern "C" void kernel_launch(void* const* d_in, const int* in_sizes, int n_in,
                              void* d_out, int out_size, void* d_ws, size_t ws_size,
                              hipStream_t stream) {
    const float* features = (const float*)d_in[0];
    const float* geometry = (const float*)d_in[1];
    const float* W1 = (const float*)d_in[2];
    const float* b1 = (const float*)d_in[3];
    const float* W2 = (const float*)d_in[4];
    const float* b2 = (const float*)d_in[5];
    float* out = (float*)d_out;

    // workspace carve: Mh (4 MB) | Ml (4 MB) | bf (128 KB)
    _Float16* Mh  = (_Float16*)d_ws;
    _Float16* Ml  = Mh + (size_t)Z * N * 2048;
    float*    bfw = (float*)(Ml + (size_t)Z * N * 2048);

    precompute_M<<<64 * 16, 64, 0, stream>>>(features, W2, b2, Mh, Ml, bfw);
    pair_contract_mfma<<<16 * Z * 64, 64, 0, stream>>>(
        geometry, W1, b1, Mh, Ml, bfw, out);
}